// Round 19
// baseline (97.792 us; speedup 1.0000x reference)
//
#include <hip/hip_runtime.h>

// Problem constants
#define NTOK 2048     // B*T
#define DIMD 768
#define HD   3072
#define NE   4

typedef __bf16 bf16;
typedef __bf16 bf16x8 __attribute__((ext_vector_type(8)));
typedef float  f32x4  __attribute__((ext_vector_type(4)));
typedef unsigned int u32;

__device__ inline ushort f2bu(float f) {
  bf16 h = (bf16)f;
  ushort u;
  __builtin_memcpy(&u, &h, 2);
  return u;
}
__device__ inline float b2f(ushort u) {
  u32 v = (u32)u << 16;
  float f;
  __builtin_memcpy(&f, &v, 4);
  return f;
}
__device__ inline u32 pk2(float lo, float hi) {
  return (u32)f2bu(lo) | ((u32)f2bu(hi) << 16);
}

// async global->LDS, 16B per lane; lds ptr must be wave-uniform
__device__ __forceinline__ void gl16(const void* g, void* l) {
  __builtin_amdgcn_global_load_lds(
      (const __attribute__((address_space(1))) u32*)g,
      (__attribute__((address_space(3))) u32*)l, 16, 0, 0);
}

// ---------------------------------------------------------------------------
// Prep: [0,2304) conv_upT (LDS 64x64 tile transpose), [2304,2816) router.
// (R17 configuration — best measured.)
// ---------------------------------------------------------------------------
__global__ __launch_bounds__(256) void k_prep(
    const float* __restrict__ x, const float* __restrict__ rw,
    const float* __restrict__ sup, const float* __restrict__ rup,
    bf16* __restrict__ xb, bf16* __restrict__ wupT,
    float* __restrict__ probs, float* __restrict__ lse,
    int* __restrict__ tok_e, float* __restrict__ tok_w)
{
  __shared__ ushort T[64][72];
  const int bid = blockIdx.x;
  const int tid = threadIdx.x;

  if (bid < 2304) {
    // ---- conv_upT: wupT[e][n][d] = bf16(sup[d][n] + rup[e][d][n]) ----
    const int e = bid / 576;
    const int r = bid % 576;
    const int n0 = (r % 48) * 64, d0 = (r / 48) * 64;
    const float* rb = rup + (size_t)e * DIMD * HD;
#pragma unroll
    for (int p = 0; p < 4; ++p) {
      int dl = p * 16 + (tid >> 4);
      int nl = (tid & 15) * 4;
      size_t gi = (size_t)(d0 + dl) * HD + (n0 + nl);
      float4 a = *(const float4*)(sup + gi);
      float4 b = *(const float4*)(rb + gi);
      T[nl + 0][dl] = f2bu(a.x + b.x);
      T[nl + 1][dl] = f2bu(a.y + b.y);
      T[nl + 2][dl] = f2bu(a.z + b.z);
      T[nl + 3][dl] = f2bu(a.w + b.w);
    }
    __syncthreads();
    bf16* ob = wupT + (size_t)e * HD * DIMD;
#pragma unroll
    for (int p = 0; p < 2; ++p) {
      int nl = p * 32 + (tid >> 3);
      int c = (tid & 7) * 8;
      uint4 v = *(const uint4*)&T[nl][c];
      *(uint4*)(ob + (size_t)(n0 + nl) * DIMD + d0 + c) = v;
    }
  } else {
    // ---- router: one wave per token ----
    const int lane = tid & 63;
    const int t = (bid - 2304) * 4 + (tid >> 6);

    const float4* xr = (const float4*)(x + (size_t)t * DIMD);
    const float4* w0 = (const float4*)(rw);
    const float4* w1 = (const float4*)(rw + DIMD);
    const float4* w2 = (const float4*)(rw + 2 * DIMD);
    const float4* w3 = (const float4*)(rw + 3 * DIMD);

    float a0 = 0.f, a1 = 0.f, a2 = 0.f, a3 = 0.f;
    float4 xv[3];
#pragma unroll
    for (int c = 0; c < 3; ++c) {
      float4 v = xr[lane + 64 * c];
      xv[c] = v;
      float4 q;
      q = w0[lane + 64 * c]; a0 += v.x*q.x + v.y*q.y + v.z*q.z + v.w*q.w;
      q = w1[lane + 64 * c]; a1 += v.x*q.x + v.y*q.y + v.z*q.z + v.w*q.w;
      q = w2[lane + 64 * c]; a2 += v.x*q.x + v.y*q.y + v.z*q.z + v.w*q.w;
      q = w3[lane + 64 * c]; a3 += v.x*q.x + v.y*q.y + v.z*q.z + v.w*q.w;
    }

    bf16* xo = xb + (size_t)t * DIMD;
#pragma unroll
    for (int c = 0; c < 3; ++c) {
      int d = 4 * (lane + 64 * c);
      ushort4 u;
      u.x = f2bu(xv[c].x); u.y = f2bu(xv[c].y);
      u.z = f2bu(xv[c].z); u.w = f2bu(xv[c].w);
      *(ushort4*)(xo + d) = u;
    }

#pragma unroll
    for (int s = 32; s > 0; s >>= 1) {
      a0 += __shfl_xor(a0, s);
      a1 += __shfl_xor(a1, s);
      a2 += __shfl_xor(a2, s);
      a3 += __shfl_xor(a3, s);
    }

    if (lane == 0) {
      float l[4] = {a0, a1, a2, a3};
      float m = fmaxf(fmaxf(l[0], l[1]), fmaxf(l[2], l[3]));
      float p[4];
      float s = 0.f;
#pragma unroll
      for (int e = 0; e < 4; ++e) { p[e] = expf(l[e] - m); s += p[e]; }
      float inv = 1.f / s;
#pragma unroll
      for (int e = 0; e < 4; ++e) p[e] *= inv;

      ((float4*)probs)[t] = make_float4(p[0], p[1], p[2], p[3]);
      lse[t] = m + logf(s);

      int i0 = 0;
#pragma unroll
      for (int e = 1; e < 4; ++e) if (l[e] > l[i0]) i0 = e;
      int i1 = -1;
#pragma unroll
      for (int e = 0; e < 4; ++e)
        if (e != i0 && (i1 < 0 || l[e] > l[i1])) i1 = e;

      float wsum = p[i0] + p[i1];
      tok_e[2 * t]     = i0;
      tok_e[2 * t + 1] = i1;
      tok_w[2 * t]     = p[i0] / wsum;
      tok_w[2 * t + 1] = p[i1] / wsum;
    }
  }
}

// ---------------------------------------------------------------------------
// Build lists (deterministic counting sort) + aux losses. One block.
// ---------------------------------------------------------------------------
__global__ __launch_bounds__(256) void k_build_fin(
    const int* __restrict__ tok_e, const float* __restrict__ probs,
    const float* __restrict__ lse,
    int* __restrict__ tok_slot, int* __restrict__ list_tok,
    int* __restrict__ cnt, int* __restrict__ base,
    float* __restrict__ out_tail)
{
  __shared__ int4 hist[256];
  __shared__ float red[256];
  const int tid = threadIdx.x;
  const int t0 = tid * 8;

  int ee[16];
  int lh[4] = {0, 0, 0, 0};
#pragma unroll
  for (int i = 0; i < 16; ++i) {
    int e = tok_e[2 * t0 + i];
    ee[i] = e;
    lh[e]++;
  }
  hist[tid] = make_int4(lh[0], lh[1], lh[2], lh[3]);
  __syncthreads();
  for (int s = 1; s < 256; s <<= 1) {
    int4 v = hist[tid];
    int4 u = make_int4(0, 0, 0, 0);
    if (tid >= s) u = hist[tid - s];
    __syncthreads();
    hist[tid] = make_int4(v.x + u.x, v.y + u.y, v.z + u.z, v.w + u.w);
    __syncthreads();
  }
  const int4 tot = hist[255];
  const int4 incl = hist[tid];
  int run[4];
  run[0] = incl.x - lh[0];
  run[1] = incl.y - lh[1];
  run[2] = incl.z - lh[2];
  run[3] = incl.w - lh[3];

#pragma unroll
  for (int i = 0; i < 16; ++i) {
    int e = ee[i];
    int s = run[e]++;
    tok_slot[2 * t0 + i] = s;
    list_tok[e * NTOK + s] = t0 + (i >> 1);
  }

  if (tid == 0) {
    cnt[0] = tot.x; cnt[1] = tot.y; cnt[2] = tot.z; cnt[3] = tot.w;
    base[0] = 0;
    base[1] = tot.x;
    base[2] = tot.x + tot.y;
    base[3] = tot.x + tot.y + tot.z;
  }

  // aux losses
  float s0 = 0, s1 = 0, s2 = 0, s3 = 0, sz = 0;
  for (int t = tid; t < NTOK; t += 256) {
    float4 p = ((const float4*)probs)[t];
    s0 += p.x; s1 += p.y; s2 += p.z; s3 += p.w;
    float L = lse[t];
    sz += L * L;
  }
  float vals[5] = {s0, s1, s2, s3, sz};
  float res[5];
#pragma unroll
  for (int q = 0; q < 5; ++q) {
    __syncthreads();
    red[tid] = vals[q];
    __syncthreads();
    for (int s = 128; s > 0; s >>= 1) {
      if (tid < s) red[tid] += red[tid + s];
      __syncthreads();
    }
    res[q] = red[0];
  }
  if (tid == 0) {
    float lb = (float)tot.x * res[0] + (float)tot.y * res[1] +
               (float)tot.z * res[2] + (float)tot.w * res[3];
    lb *= (float)NE / ((float)NTOK * (float)NTOK);
    out_tail[0] = lb;
    out_tail[1] = res[4] / (float)NTOK;
  }
}

// ---------------------------------------------------------------------------
// Up GEMM + conv_dn filler. GEMM: 128x128 tile, BK=32, DOUBLE-BUFFERED
// (2 x 16KB LDS -> 4 blocks/CU; prefetch stays in flight across barrier).
// Rows 64B; stage swizzle c=(lane&3)^((lane>>3)&3); read sl=(koff^((fr>>1)&3)).
// relu^2 -> bf16 hact via LDS-staged coalesced epilogue. XCD-pinned.
// ---------------------------------------------------------------------------
__global__ __launch_bounds__(256, 4) void k_gemm_up(
    const bf16* __restrict__ xb, const bf16* __restrict__ wupT,
    const int* __restrict__ list_tok, const int* __restrict__ cnt,
    const int* __restrict__ base, bf16* __restrict__ hact,
    const float* __restrict__ sdn, const float* __restrict__ rdn,
    bf16* __restrict__ wdn)
{
  __shared__ char lds[32768];
  const int bid = blockIdx.x;          // 3840 blocks
  const int tid = threadIdx.x;

  if (bid >= 1536) {
    // ---- conv_dn filler: wdn[e][n][h] = bf16(sdn + rdn[e]) ----
    const int idx = bid - 1536;        // [0,2304)
    const int e = idx / 576;
    const int xblk = idx % 576;
    const float4* s4 = (const float4*)sdn;
    const float4* r4 = (const float4*)(rdn + (size_t)e * DIMD * HD);
    uint4* o4 = (uint4*)(wdn + (size_t)e * DIMD * HD);
    const int gid = xblk * 256 + tid;
#pragma unroll
    for (int h = 0; h < 2; ++h) {
      int i = gid + h * 147456;        // 294912 8-elem chunks per expert
      float4 a0 = s4[2 * i], a1 = s4[2 * i + 1];
      float4 b0 = r4[2 * i], b1 = r4[2 * i + 1];
      uint4 o;
      o.x = pk2(a0.x + b0.x, a0.y + b0.y);
      o.y = pk2(a0.z + b0.z, a0.w + b0.w);
      o.z = pk2(a1.x + b1.x, a1.y + b1.y);
      o.w = pk2(a1.z + b1.z, a1.w + b1.w);
      o4[i] = o;
    }
    return;
  }

  const int xcd = bid & 7;
  const int e = xcd >> 1;
  const int sub = ((bid >> 3) << 1) | (xcd & 1);   // [0,384) per expert
  const int n0 = (sub % 24) * 128;
  const int m0 = (sub / 24) * 128;
  const int cn = cnt[e];
  if (m0 >= cn) return;

  const int lane = tid & 63;
  const int wave = tid >> 6;
  const int wr = wave >> 1, wc = wave & 1;

  const bf16* Bb = wupT + (size_t)e * HD * DIMD;

  // staging: rows 64B; thread covers rows wave*32 + j*16 + (lane>>2), unit lane&3
  // pre-swizzled source slice: c = (lane&3) ^ ((lane>>3)&3)  [= (row>>1)&3]
  const int csw = ((lane & 3) ^ ((lane >> 3) & 3)) * 16;
  const char* apt[2];
  const char* bpt[2];
#pragma unroll
  for (int j = 0; j < 2; ++j) {
    int row = wave * 32 + j * 16 + (lane >> 2);
    int ar = m0 + row; if (ar > cn - 1) ar = cn - 1;
    int tok = list_tok[e * NTOK + ar];
    apt[j] = (const char*)(xb + (size_t)tok * DIMD) + csw;
    bpt[j] = (const char*)(Bb + (size_t)(n0 + row) * DIMD) + csw;
  }

  auto stage = [&](int b, int kt) {
    char* la = lds + b * 16384 + wave * 2048;
    char* lb = la + 8192;
    const int o = kt * 64;             // 32 bf16 per row per K-step
#pragma unroll
    for (int j = 0; j < 2; ++j) {
      gl16(apt[j] + o, la + j * 1024);
      gl16(bpt[j] + o, lb + j * 1024);
    }
  };

  f32x4 acc[4][4] = {};
  const int koff = lane >> 4;
  const int fr = lane & 15;
  const int frs = (fr >> 1) & 3;
  const int sl = (koff ^ frs) * 16;

  stage(0, 0);
  const int NT = DIMD / 32;  // 24
  int cur = 0;
  for (int kt = 0; kt < NT; ++kt) {
    __syncthreads();
    if (kt + 1 < NT) stage(cur ^ 1, kt + 1);
    const char* Ab = lds + cur * 16384;
    const char* Bc = Ab + 8192;
    bf16x8 af[4], bq[4];
#pragma unroll
    for (int m = 0; m < 4; ++m)
      af[m] = *(const bf16x8*)(Ab + (wr * 64 + m * 16 + fr) * 64 + sl);
#pragma unroll
    for (int n = 0; n < 4; ++n)
      bq[n] = *(const bf16x8*)(Bc + (wc * 64 + n * 16 + fr) * 64 + sl);
    __builtin_amdgcn_s_setprio(1);
#pragma unroll
    for (int m = 0; m < 4; ++m)
#pragma unroll
      for (int n = 0; n < 4; ++n)
        acc[m][n] = __builtin_amdgcn_mfma_f32_16x16x32_bf16(af[m], bq[n], acc[m][n], 0, 0, 0);
    __builtin_amdgcn_s_setprio(0);
    cur ^= 1;
  }
  __syncthreads();

  const int ba = base[e];
  {
    char* C = lds;
    const int cg = lane & 15, rq = lane >> 4;
#pragma unroll
    for (int m = 0; m < 4; ++m) {
#pragma unroll
      for (int q = 0; q < 4; ++q) {
        const int row = wr * 64 + m * 16 + rq * 4 + q;
        const int swz = ((row >> 2) & 3) << 5;
#pragma unroll
        for (int n = 0; n < 4; ++n) {
          const int col = wc * 64 + n * 16 + cg;
          float h = acc[m][n][q];
          float rl = fmaxf(h, 0.f);
          *(ushort*)(C + row * 256 + ((col * 2) ^ swz)) = f2bu(rl * rl);
        }
      }
    }
  }
  __syncthreads();
  {
    const int u = tid & 15;
#pragma unroll
    for (int p = 0; p < 8; ++p) {
      const int row = p * 16 + (tid >> 4);
      const int gr = m0 + row;
      if (gr < cn) {
        const int swz = ((row >> 2) & 3) << 5;
        uint4 v = *(const uint4*)(lds + row * 256 + ((u * 16) ^ swz));
        *(uint4*)((char*)(hact + (size_t)(ba + gr) * HD + n0) + u * 16) = v;
      }
    }
  }
}

// ---------------------------------------------------------------------------
// Down GEMM: 128x128 tile, BK=32, split-K=2, XCD-pinned (group g -> XCD g).
// Double-buffered 2x16KB (4 blocks/CU). bf16 partials, LDS-staged epilogue.
// ---------------------------------------------------------------------------
__global__ __launch_bounds__(256, 4) void k_gemm_dn(
    const bf16* __restrict__ hact, const bf16* __restrict__ wdn,
    const int* __restrict__ cnt, const int* __restrict__ base,
    bf16* __restrict__ yc2)
{
  const int bid = blockIdx.x;          // 768 blocks
  const int g = bid & 7;
  const int e = g >> 1, kh = g & 1;
  const int q = bid >> 3;              // [0,96) per group
  const int n0 = (q % 6) * 128;
  const int m0 = (q / 6) * 128;
  const int cn = cnt[e];
  if (m0 >= cn) return;

  __shared__ char lds[32768];

  const int tid = threadIdx.x;
  const int lane = tid & 63;
  const int wave = tid >> 6;
  const int wr = wave >> 1, wc = wave & 1;
  const int ba = base[e];
  const size_t kofs = (size_t)kh * (HD / 2);

  const int csw = ((lane & 3) ^ ((lane >> 3) & 3)) * 16;
  const char* apt[2];
  const char* bpt[2];
#pragma unroll
  for (int j = 0; j < 2; ++j) {
    int row = wave * 32 + j * 16 + (lane >> 2);
    int ar = m0 + row; if (ar > cn - 1) ar = cn - 1;
    apt[j] = (const char*)(hact + (size_t)(ba + ar) * HD + kofs) + csw;
    bpt[j] = (const char*)(wdn + (size_t)e * DIMD * HD + (size_t)(n0 + row) * HD + kofs) + csw;
  }

  auto stage = [&](int b, int kt) {
    char* la = lds + b * 16384 + wave * 2048;
    char* lb = la + 8192;
    const int o = kt * 64;
#pragma unroll
    for (int j = 0; j < 2; ++j) {
      gl16(apt[j] + o, la + j * 1024);
      gl16(bpt[j] + o, lb + j * 1024);
    }
  };

  f32x4 acc[4][4] = {};
  const int koff = lane >> 4;
  const int fr = lane & 15;
  const int frs = (fr >> 1) & 3;
  const int sl = (koff ^ frs) * 16;

  stage(0, 0);
  const int NT = (HD / 2) / 32;  // 48
  int cur = 0;
  for (int kt = 0; kt < NT; ++kt) {
    __syncthreads();
    if (kt + 1 < NT) stage(cur ^ 1, kt + 1);
    const char* Ab = lds + cur * 16384;
    const char* Bc = Ab + 8192;
    bf16x8 af[4], bq[4];
#pragma unroll
    for (int m = 0; m < 4; ++m)
      af[m] = *(const bf16x8*)(Ab + (wr * 64 + m * 16 + fr) * 64 + sl);
#pragma unroll
    for (int n = 0; n < 4; ++n)
      bq[n] = *(const bf16x8*)(Bc + (wc * 64 + n * 16 + fr) * 64 + sl);
#pragma unroll
    for (int m = 0; m < 4; ++m)
#pragma unroll
      for (int n = 0; n < 4; ++n)
        acc[m][n] = __builtin_amdgcn_mfma_f32_16x16x32_bf16(af[m], bq[n], acc[m][n], 0, 0, 0);
    cur ^= 1;
  }
  __syncthreads();   // LDS reuse for C tile

  bf16* yp = yc2 + (size_t)kh * 4096 * DIMD;
  {
    char* C = lds;
    const int cg = lane & 15, rq = lane >> 4;
#pragma unroll
    for (int m = 0; m < 4; ++m) {
#pragma unroll
      for (int q2 = 0; q2 < 4; ++q2) {
        const int row = wr * 64 + m * 16 + rq * 4 + q2;
        const int swz = ((row >> 2) & 3) << 5;
#pragma unroll
        for (int n = 0; n < 4; ++n) {
          const int col = wc * 64 + n * 16 + cg;
          *(ushort*)(C + row * 256 + ((col * 2) ^ swz)) = f2bu(acc[m][n][q2]);
        }
      }
    }
  }
  __syncthreads();
  {
    const int u = tid & 15;
#pragma unroll
    for (int p = 0; p < 8; ++p) {
      const int row = p * 16 + (tid >> 4);
      const int gr = m0 + row;
      if (gr < cn) {
        const int swz = ((row >> 2) & 3) << 5;
        uint4 v = *(const uint4*)(lds + row * 256 + ((u * 16) ^ swz));
        *(uint4*)((char*)(yp + (size_t)(ba + gr) * DIMD + n0) + u * 16) = v;
      }
    }
  }
}

// ---------------------------------------------------------------------------
// Combine: out[t] = w0*(yc2[0][p0]+yc2[1][p0]) + w1*(yc2[0][p1]+yc2[1][p1])
// ---------------------------------------------------------------------------
__global__ __launch_bounds__(192) void k_combine(
    const bf16* __restrict__ yc2, const int* __restrict__ tok_e,
    const int* __restrict__ tok_slot, const float* __restrict__ tok_w,
    const int* __restrict__ base, float* __restrict__ out)
{
  const int t = blockIdx.x;
  const int e0 = tok_e[2 * t], e1 = tok_e[2 * t + 1];
  const int p0 = base[e0] + tok_slot[2 * t];
  const int p1 = base[e1] + tok_slot[2 * t + 1];
  const float w0 = tok_w[2 * t], w1 = tok_w[2 * t + 1];
  const size_t half = (size_t)4096 * DIMD;
  const ushort4* a0 = (const ushort4*)(yc2 + (size_t)p0 * DIMD);
  const ushort4* a1 = (const ushort4*)(yc2 + half + (size_t)p0 * DIMD);
  const ushort4* b0 = (const ushort4*)(yc2 + (size_t)p1 * DIMD);
  const ushort4* b1 = (const ushort4*)(yc2 + half + (size_t)p1 * DIMD);
  float4* o = (float4*)(out + (size_t)t * DIMD);
  const int i = threadIdx.x;  // 192 threads * 4 elems = 768
  ushort4 va0 = a0[i], va1 = a1[i], vb0 = b0[i], vb1 = b1[i];
  o[i] = make_float4(
      w0 * (b2f(va0.x) + b2f(va1.x)) + w1 * (b2f(vb0.x) + b2f(vb1.x)),
      w0 * (b2f(va0.y) + b2f(va1.y)) + w1 * (b2f(vb0.y) + b2f(vb1.y)),
      w0 * (b2f(va0.z) + b2f(va1.z)) + w1 * (b2f(vb0.z) + b2f(vb1.z)),
      w0 * (b2f(va0.w) + b2f(va1.w)) + w1 * (b2f(vb0.w) + b2f(vb1.w)));
}

// ---------------------------------------------------------------------------
extern "C" void kernel_launch(void* const* d_in, const int* in_sizes, int n_in,
                              void* d_out, int out_size, void* d_ws, size_t ws_size,
                              hipStream_t stream)
{
  const float* x   = (const float*)d_in[0];
  const float* rw  = (const float*)d_in[1];
  const float* sup = (const float*)d_in[2];
  const float* sdn = (const float*)d_in[3];
  const float* rup = (const float*)d_in[4];
  const float* rdn = (const float*)d_in[5];
  float* out = (float*)d_out;

  char* w = (char*)d_ws;
  bf16*  xb       = (bf16*)(w + 0);           //  3,145,728 B
  bf16*  wupT     = (bf16*)(w + 3145728);     // 18,874,368 B  [4][3072][768]
  bf16*  wdn      = (bf16*)(w + 22020096);    // 18,874,368 B
  bf16*  hact     = (bf16*)(w + 40894464);    // 25,165,824 B
  bf16*  yc2      = (bf16*)(w + 66060288);    // 12,582,912 B  [2][4096][768]
  float* probs    = (float*)(w + 78643200);
  float* lse      = (float*)(w + 78675968);
  int*   tok_e    = (int*)(w + 78684160);
  int*   tok_slot = (int*)(w + 78700544);
  float* tok_w    = (float*)(w + 78716928);
  int*   list_tok = (int*)(w + 78733312);
  int*   cnt      = (int*)(w + 78766080);
  int*   base     = (int*)(w + 78766336);

  k_prep<<<2816, 256, 0, stream>>>(x, rw, sup, rup, xb, wupT,
                                   probs, lse, tok_e, tok_w);
  k_build_fin<<<1, 256, 0, stream>>>(tok_e, probs, lse, tok_slot, list_tok,
                                     cnt, base, out + (size_t)NTOK * DIMD);
  k_gemm_up<<<3840, 256, 0, stream>>>(xb, wupT, list_tok, cnt, base, hact,
                                      sdn, rdn, wdn);
  k_gemm_dn<<<768, 256, 0, stream>>>(hact, wdn, cnt, base, yc2);
  k_combine<<<2048, 192, 0, stream>>>(yc2, tok_e, tok_slot, tok_w, base, out);
}

// Round 20
// 88.696 us; speedup vs baseline: 1.1026x; 1.1026x over previous
//
#include <hip/hip_runtime.h>

// Problem constants
#define NTOK 2048     // B*T
#define DIMD 768
#define HD   3072
#define NE   4

typedef __bf16 bf16;
typedef __bf16 bf16x8 __attribute__((ext_vector_type(8)));
typedef float  f32x4  __attribute__((ext_vector_type(4)));
typedef unsigned int u32;

__device__ inline ushort f2bu(float f) {
  bf16 h = (bf16)f;
  ushort u;
  __builtin_memcpy(&u, &h, 2);
  return u;
}
__device__ inline float b2f(ushort u) {
  u32 v = (u32)u << 16;
  float f;
  __builtin_memcpy(&f, &v, 4);
  return f;
}
__device__ inline u32 pk2(float lo, float hi) {
  return (u32)f2bu(lo) | ((u32)f2bu(hi) << 16);
}

// async global->LDS, 16B per lane; lds ptr must be wave-uniform
__device__ __forceinline__ void gl16(const void* g, void* l) {
  __builtin_amdgcn_global_load_lds(
      (const __attribute__((address_space(1))) u32*)g,
      (__attribute__((address_space(3))) u32*)l, 16, 0, 0);
}

// ---------------------------------------------------------------------------
// Prep: [0,2304) conv_upT (LDS 64x64 tile transpose), [2304,2816) router.
// conv_dn lives in the gemm_up launch as back-loaded filler blocks.
// ---------------------------------------------------------------------------
__global__ __launch_bounds__(256) void k_prep(
    const float* __restrict__ x, const float* __restrict__ rw,
    const float* __restrict__ sup, const float* __restrict__ rup,
    bf16* __restrict__ xb, bf16* __restrict__ wupT,
    float* __restrict__ probs, float* __restrict__ lse,
    int* __restrict__ tok_e, float* __restrict__ tok_w)
{
  __shared__ ushort T[64][72];
  const int bid = blockIdx.x;
  const int tid = threadIdx.x;

  if (bid < 2304) {
    // ---- conv_upT: wupT[e][n][d] = bf16(sup[d][n] + rup[e][d][n]) ----
    const int e = bid / 576;
    const int r = bid % 576;
    const int n0 = (r % 48) * 64, d0 = (r / 48) * 64;
    const float* rb = rup + (size_t)e * DIMD * HD;
#pragma unroll
    for (int p = 0; p < 4; ++p) {
      int dl = p * 16 + (tid >> 4);
      int nl = (tid & 15) * 4;
      size_t gi = (size_t)(d0 + dl) * HD + (n0 + nl);
      float4 a = *(const float4*)(sup + gi);
      float4 b = *(const float4*)(rb + gi);
      T[nl + 0][dl] = f2bu(a.x + b.x);
      T[nl + 1][dl] = f2bu(a.y + b.y);
      T[nl + 2][dl] = f2bu(a.z + b.z);
      T[nl + 3][dl] = f2bu(a.w + b.w);
    }
    __syncthreads();
    bf16* ob = wupT + (size_t)e * HD * DIMD;
#pragma unroll
    for (int p = 0; p < 2; ++p) {
      int nl = p * 32 + (tid >> 3);
      int c = (tid & 7) * 8;
      uint4 v = *(const uint4*)&T[nl][c];
      *(uint4*)(ob + (size_t)(n0 + nl) * DIMD + d0 + c) = v;
    }
  } else {
    // ---- router: one wave per token ----
    const int lane = tid & 63;
    const int t = (bid - 2304) * 4 + (tid >> 6);

    const float4* xr = (const float4*)(x + (size_t)t * DIMD);
    const float4* w0 = (const float4*)(rw);
    const float4* w1 = (const float4*)(rw + DIMD);
    const float4* w2 = (const float4*)(rw + 2 * DIMD);
    const float4* w3 = (const float4*)(rw + 3 * DIMD);

    float a0 = 0.f, a1 = 0.f, a2 = 0.f, a3 = 0.f;
    float4 xv[3];
#pragma unroll
    for (int c = 0; c < 3; ++c) {
      float4 v = xr[lane + 64 * c];
      xv[c] = v;
      float4 q;
      q = w0[lane + 64 * c]; a0 += v.x*q.x + v.y*q.y + v.z*q.z + v.w*q.w;
      q = w1[lane + 64 * c]; a1 += v.x*q.x + v.y*q.y + v.z*q.z + v.w*q.w;
      q = w2[lane + 64 * c]; a2 += v.x*q.x + v.y*q.y + v.z*q.z + v.w*q.w;
      q = w3[lane + 64 * c]; a3 += v.x*q.x + v.y*q.y + v.z*q.z + v.w*q.w;
    }

    bf16* xo = xb + (size_t)t * DIMD;
#pragma unroll
    for (int c = 0; c < 3; ++c) {
      int d = 4 * (lane + 64 * c);
      ushort4 u;
      u.x = f2bu(xv[c].x); u.y = f2bu(xv[c].y);
      u.z = f2bu(xv[c].z); u.w = f2bu(xv[c].w);
      *(ushort4*)(xo + d) = u;
    }

#pragma unroll
    for (int s = 32; s > 0; s >>= 1) {
      a0 += __shfl_xor(a0, s);
      a1 += __shfl_xor(a1, s);
      a2 += __shfl_xor(a2, s);
      a3 += __shfl_xor(a3, s);
    }

    if (lane == 0) {
      float l[4] = {a0, a1, a2, a3};
      float m = fmaxf(fmaxf(l[0], l[1]), fmaxf(l[2], l[3]));
      float p[4];
      float s = 0.f;
#pragma unroll
      for (int e = 0; e < 4; ++e) { p[e] = expf(l[e] - m); s += p[e]; }
      float inv = 1.f / s;
#pragma unroll
      for (int e = 0; e < 4; ++e) p[e] *= inv;

      ((float4*)probs)[t] = make_float4(p[0], p[1], p[2], p[3]);
      lse[t] = m + logf(s);

      int i0 = 0;
#pragma unroll
      for (int e = 1; e < 4; ++e) if (l[e] > l[i0]) i0 = e;
      int i1 = -1;
#pragma unroll
      for (int e = 0; e < 4; ++e)
        if (e != i0 && (i1 < 0 || l[e] > l[i1])) i1 = e;

      float wsum = p[i0] + p[i1];
      tok_e[2 * t]     = i0;
      tok_e[2 * t + 1] = i1;
      tok_w[2 * t]     = p[i0] / wsum;
      tok_w[2 * t + 1] = p[i1] / wsum;
    }
  }
}

// ---------------------------------------------------------------------------
// Build lists (deterministic counting sort) + aux losses. One block.
// ---------------------------------------------------------------------------
__global__ __launch_bounds__(256) void k_build_fin(
    const int* __restrict__ tok_e, const float* __restrict__ probs,
    const float* __restrict__ lse,
    int* __restrict__ tok_slot, int* __restrict__ list_tok,
    int* __restrict__ cnt, int* __restrict__ base,
    float* __restrict__ out_tail)
{
  __shared__ int4 hist[256];
  __shared__ float red[256];
  const int tid = threadIdx.x;
  const int t0 = tid * 8;

  int ee[16];
  int lh[4] = {0, 0, 0, 0};
#pragma unroll
  for (int i = 0; i < 16; ++i) {
    int e = tok_e[2 * t0 + i];
    ee[i] = e;
    lh[e]++;
  }
  hist[tid] = make_int4(lh[0], lh[1], lh[2], lh[3]);
  __syncthreads();
  for (int s = 1; s < 256; s <<= 1) {
    int4 v = hist[tid];
    int4 u = make_int4(0, 0, 0, 0);
    if (tid >= s) u = hist[tid - s];
    __syncthreads();
    hist[tid] = make_int4(v.x + u.x, v.y + u.y, v.z + u.z, v.w + u.w);
    __syncthreads();
  }
  const int4 tot = hist[255];
  const int4 incl = hist[tid];
  int run[4];
  run[0] = incl.x - lh[0];
  run[1] = incl.y - lh[1];
  run[2] = incl.z - lh[2];
  run[3] = incl.w - lh[3];

#pragma unroll
  for (int i = 0; i < 16; ++i) {
    int e = ee[i];
    int s = run[e]++;
    tok_slot[2 * t0 + i] = s;
    list_tok[e * NTOK + s] = t0 + (i >> 1);
  }

  if (tid == 0) {
    cnt[0] = tot.x; cnt[1] = tot.y; cnt[2] = tot.z; cnt[3] = tot.w;
    base[0] = 0;
    base[1] = tot.x;
    base[2] = tot.x + tot.y;
    base[3] = tot.x + tot.y + tot.z;
  }

  // aux losses
  float s0 = 0, s1 = 0, s2 = 0, s3 = 0, sz = 0;
  for (int t = tid; t < NTOK; t += 256) {
    float4 p = ((const float4*)probs)[t];
    s0 += p.x; s1 += p.y; s2 += p.z; s3 += p.w;
    float L = lse[t];
    sz += L * L;
  }
  float vals[5] = {s0, s1, s2, s3, sz};
  float res[5];
#pragma unroll
  for (int q = 0; q < 5; ++q) {
    __syncthreads();
    red[tid] = vals[q];
    __syncthreads();
    for (int s = 128; s > 0; s >>= 1) {
      if (tid < s) red[tid] += red[tid + s];
      __syncthreads();
    }
    res[q] = red[0];
  }
  if (tid == 0) {
    float lb = (float)tot.x * res[0] + (float)tot.y * res[1] +
               (float)tot.z * res[2] + (float)tot.w * res[3];
    lb *= (float)NE / ((float)NTOK * (float)NTOK);
    out_tail[0] = lb;
    out_tail[1] = res[4] / (float)NTOK;
  }
}

// ---------------------------------------------------------------------------
// Up GEMM + conv_dn filler (merged launch, back-loaded fillers):
//  bid < 1536:  128x128 GEMM tile, BK=64, double-buffered gl16 staging,
//               XOR-swizzled ds_read_b128, relu^2 -> bf16 hact; XCD-pinned.
//               setprio(1) around the MFMA cluster.
//  bid >= 1536: conv_dn streaming filler blocks -> wdn.
// ---------------------------------------------------------------------------
__global__ __launch_bounds__(256, 2) void k_gemm_up(
    const bf16* __restrict__ xb, const bf16* __restrict__ wupT,
    const int* __restrict__ list_tok, const int* __restrict__ cnt,
    const int* __restrict__ base, bf16* __restrict__ hact,
    const float* __restrict__ sdn, const float* __restrict__ rdn,
    bf16* __restrict__ wdn)
{
  __shared__ char lds[65536];
  const int bid = blockIdx.x;          // 3840 blocks
  const int tid = threadIdx.x;

  if (bid >= 1536) {
    // ---- conv_dn filler: wdn[e][n][h] = bf16(sdn + rdn[e]) ----
    const int idx = bid - 1536;        // [0,2304)
    const int e = idx / 576;
    const int xblk = idx % 576;
    const float4* s4 = (const float4*)sdn;
    const float4* r4 = (const float4*)(rdn + (size_t)e * DIMD * HD);
    uint4* o4 = (uint4*)(wdn + (size_t)e * DIMD * HD);
    const int gid = xblk * 256 + tid;
#pragma unroll
    for (int h = 0; h < 2; ++h) {
      int i = gid + h * 147456;        // 294912 8-elem chunks per expert
      float4 a0 = s4[2 * i], a1 = s4[2 * i + 1];
      float4 b0 = r4[2 * i], b1 = r4[2 * i + 1];
      uint4 o;
      o.x = pk2(a0.x + b0.x, a0.y + b0.y);
      o.y = pk2(a0.z + b0.z, a0.w + b0.w);
      o.z = pk2(a1.x + b1.x, a1.y + b1.y);
      o.w = pk2(a1.z + b1.z, a1.w + b1.w);
      o4[i] = o;
    }
    return;
  }

  const int xcd = bid & 7;
  const int e = xcd >> 1;
  const int sub = ((bid >> 3) << 1) | (xcd & 1);   // [0,384) per expert
  const int n0 = (sub % 24) * 128;
  const int m0 = (sub / 24) * 128;
  const int cn = cnt[e];
  if (m0 >= cn) return;

  const int lane = tid & 63;
  const int wave = tid >> 6;
  const int wr = wave >> 1, wc = wave & 1;

  const bf16* Bb = wupT + (size_t)e * HD * DIMD;

  const int c16 = ((lane & 7) ^ (lane >> 3)) * 16;
  const char* apt[4];
  const char* bpt[4];
#pragma unroll
  for (int j = 0; j < 4; ++j) {
    int row = (wave * 4 + j) * 8 + (lane >> 3);
    int ar = m0 + row; if (ar > cn - 1) ar = cn - 1;
    int tok = list_tok[e * NTOK + ar];
    apt[j] = (const char*)(xb + (size_t)tok * DIMD) + c16;
    bpt[j] = (const char*)(Bb + (size_t)(n0 + row) * DIMD) + c16;
  }

  auto stage = [&](int b, int kt) {
    char* la = lds + b * 32768 + (wave * 4) * 1024;
    char* lb = la + 16384;
    const int o = kt * 128;
#pragma unroll
    for (int j = 0; j < 4; ++j) {
      gl16(apt[j] + o, la + j * 1024);
      gl16(bpt[j] + o, lb + j * 1024);
    }
  };

  f32x4 acc[4][4] = {};
  const int koff = lane >> 4;
  const int xr = lane & 7;
  const int fr = lane & 15;

  stage(0, 0);
  const int NT = DIMD * 2 / 128;  // 12
  int cur = 0;
  for (int kt = 0; kt < NT; ++kt) {
    __syncthreads();
    if (kt + 1 < NT) stage(cur ^ 1, kt + 1);
    const char* Ab = lds + cur * 32768;
    const char* Bc = Ab + 16384;
#pragma unroll
    for (int ks = 0; ks < 2; ++ks) {
      const int sl = ((ks * 4 + koff) ^ xr) * 16;
      bf16x8 af[4], bq[4];
#pragma unroll
      for (int m = 0; m < 4; ++m)
        af[m] = *(const bf16x8*)(Ab + (wr * 64 + m * 16 + fr) * 128 + sl);
#pragma unroll
      for (int n = 0; n < 4; ++n)
        bq[n] = *(const bf16x8*)(Bc + (wc * 64 + n * 16 + fr) * 128 + sl);
      __builtin_amdgcn_s_setprio(1);
#pragma unroll
      for (int m = 0; m < 4; ++m)
#pragma unroll
        for (int n = 0; n < 4; ++n)
          acc[m][n] = __builtin_amdgcn_mfma_f32_16x16x32_bf16(af[m], bq[n], acc[m][n], 0, 0, 0);
      __builtin_amdgcn_s_setprio(0);
    }
    cur ^= 1;
  }
  __syncthreads();

  const int ba = base[e];
  {
    char* C = lds;
    const int cg = lane & 15, rq = lane >> 4;
#pragma unroll
    for (int m = 0; m < 4; ++m) {
#pragma unroll
      for (int q = 0; q < 4; ++q) {
        const int row = wr * 64 + m * 16 + rq * 4 + q;
        const int swz = ((row >> 2) & 3) << 5;
#pragma unroll
        for (int n = 0; n < 4; ++n) {
          const int col = wc * 64 + n * 16 + cg;
          float h = acc[m][n][q];
          float rl = fmaxf(h, 0.f);
          *(ushort*)(C + row * 256 + ((col * 2) ^ swz)) = f2bu(rl * rl);
        }
      }
    }
  }
  __syncthreads();
  {
    const int u = tid & 15;
#pragma unroll
    for (int p = 0; p < 8; ++p) {
      const int row = p * 16 + (tid >> 4);
      const int gr = m0 + row;
      if (gr < cn) {
        const int swz = ((row >> 2) & 3) << 5;
        uint4 v = *(const uint4*)(lds + row * 256 + ((u * 16) ^ swz));
        *(uint4*)((char*)(hact + (size_t)(ba + gr) * HD + n0) + u * 16) = v;
      }
    }
  }
}

// ---------------------------------------------------------------------------
// Down GEMM: 128x128 tile, BK=64, split-K=2, XCD-pinned (group g -> XCD g).
// Double-buffered. bf16 partials via LDS-staged coalesced epilogue.
// ---------------------------------------------------------------------------
__global__ __launch_bounds__(256, 2) void k_gemm_dn(
    const bf16* __restrict__ hact, const bf16* __restrict__ wdn,
    const int* __restrict__ cnt, const int* __restrict__ base,
    bf16* __restrict__ yc2)
{
  const int bid = blockIdx.x;          // 768 blocks
  const int g = bid & 7;
  const int e = g >> 1, kh = g & 1;
  const int q = bid >> 3;              // [0,96) per group
  const int n0 = (q % 6) * 128;
  const int m0 = (q / 6) * 128;
  const int cn = cnt[e];
  if (m0 >= cn) return;

  __shared__ char lds[65536];

  const int tid = threadIdx.x;
  const int lane = tid & 63;
  const int wave = tid >> 6;
  const int wr = wave >> 1, wc = wave & 1;
  const int ba = base[e];
  const size_t kofs = (size_t)kh * (HD / 2);

  const int c16 = ((lane & 7) ^ (lane >> 3)) * 16;
  const char* apt[4];
  const char* bpt[4];
#pragma unroll
  for (int j = 0; j < 4; ++j) {
    int row = (wave * 4 + j) * 8 + (lane >> 3);
    int ar = m0 + row; if (ar > cn - 1) ar = cn - 1;
    apt[j] = (const char*)(hact + (size_t)(ba + ar) * HD + kofs) + c16;
    bpt[j] = (const char*)(wdn + (size_t)e * DIMD * HD + (size_t)(n0 + row) * HD + kofs) + c16;
  }

  auto stage = [&](int b, int kt) {
    char* la = lds + b * 32768 + (wave * 4) * 1024;
    char* lb = la + 16384;
    const int o = kt * 128;
#pragma unroll
    for (int j = 0; j < 4; ++j) {
      gl16(apt[j] + o, la + j * 1024);
      gl16(bpt[j] + o, lb + j * 1024);
    }
  };

  f32x4 acc[4][4] = {};
  const int koff = lane >> 4;
  const int xr = lane & 7;
  const int fr = lane & 15;

  stage(0, 0);
  const int NT = HD / 128;  // 24 K-steps of 64 (half of K=3072)
  int cur = 0;
  for (int kt = 0; kt < NT; ++kt) {
    __syncthreads();
    if (kt + 1 < NT) stage(cur ^ 1, kt + 1);
    const char* Ab = lds + cur * 32768;
    const char* Bc = Ab + 16384;
#pragma unroll
    for (int ks = 0; ks < 2; ++ks) {
      const int sl = ((ks * 4 + koff) ^ xr) * 16;
      bf16x8 af[4], bq[4];
#pragma unroll
      for (int m = 0; m < 4; ++m)
        af[m] = *(const bf16x8*)(Ab + (wr * 64 + m * 16 + fr) * 128 + sl);
#pragma unroll
      for (int n = 0; n < 4; ++n)
        bq[n] = *(const bf16x8*)(Bc + (wc * 64 + n * 16 + fr) * 128 + sl);
#pragma unroll
      for (int m = 0; m < 4; ++m)
#pragma unroll
        for (int n = 0; n < 4; ++n)
          acc[m][n] = __builtin_amdgcn_mfma_f32_16x16x32_bf16(af[m], bq[n], acc[m][n], 0, 0, 0);
    }
    cur ^= 1;
  }
  __syncthreads();   // LDS reuse for C tile

  bf16* yp = yc2 + (size_t)kh * 4096 * DIMD;
  {
    char* C = lds;
    const int cg = lane & 15, rq = lane >> 4;
#pragma unroll
    for (int m = 0; m < 4; ++m) {
#pragma unroll
      for (int q2 = 0; q2 < 4; ++q2) {
        const int row = wr * 64 + m * 16 + rq * 4 + q2;
        const int swz = ((row >> 2) & 3) << 5;
#pragma unroll
        for (int n = 0; n < 4; ++n) {
          const int col = wc * 64 + n * 16 + cg;
          *(ushort*)(C + row * 256 + ((col * 2) ^ swz)) = f2bu(acc[m][n][q2]);
        }
      }
    }
  }
  __syncthreads();
  {
    const int u = tid & 15;
#pragma unroll
    for (int p = 0; p < 8; ++p) {
      const int row = p * 16 + (tid >> 4);
      const int gr = m0 + row;
      if (gr < cn) {
        const int swz = ((row >> 2) & 3) << 5;
        uint4 v = *(const uint4*)(lds + row * 256 + ((u * 16) ^ swz));
        *(uint4*)((char*)(yp + (size_t)(ba + gr) * DIMD + n0) + u * 16) = v;
      }
    }
  }
}

// ---------------------------------------------------------------------------
// Combine: out[t] = w0*(yc2[0][p0]+yc2[1][p0]) + w1*(yc2[0][p1]+yc2[1][p1])
// ---------------------------------------------------------------------------
__global__ __launch_bounds__(192) void k_combine(
    const bf16* __restrict__ yc2, const int* __restrict__ tok_e,
    const int* __restrict__ tok_slot, const float* __restrict__ tok_w,
    const int* __restrict__ base, float* __restrict__ out)
{
  const int t = blockIdx.x;
  const int e0 = tok_e[2 * t], e1 = tok_e[2 * t + 1];
  const int p0 = base[e0] + tok_slot[2 * t];
  const int p1 = base[e1] + tok_slot[2 * t + 1];
  const float w0 = tok_w[2 * t], w1 = tok_w[2 * t + 1];
  const size_t half = (size_t)4096 * DIMD;
  const ushort4* a0 = (const ushort4*)(yc2 + (size_t)p0 * DIMD);
  const ushort4* a1 = (const ushort4*)(yc2 + half + (size_t)p0 * DIMD);
  const ushort4* b0 = (const ushort4*)(yc2 + (size_t)p1 * DIMD);
  const ushort4* b1 = (const ushort4*)(yc2 + half + (size_t)p1 * DIMD);
  float4* o = (float4*)(out + (size_t)t * DIMD);
  const int i = threadIdx.x;  // 192 threads * 4 elems = 768
  ushort4 va0 = a0[i], va1 = a1[i], vb0 = b0[i], vb1 = b1[i];
  o[i] = make_float4(
      w0 * (b2f(va0.x) + b2f(va1.x)) + w1 * (b2f(vb0.x) + b2f(vb1.x)),
      w0 * (b2f(va0.y) + b2f(va1.y)) + w1 * (b2f(vb0.y) + b2f(vb1.y)),
      w0 * (b2f(va0.z) + b2f(va1.z)) + w1 * (b2f(vb0.z) + b2f(vb1.z)),
      w0 * (b2f(va0.w) + b2f(va1.w)) + w1 * (b2f(vb0.w) + b2f(vb1.w)));
}

// ---------------------------------------------------------------------------
extern "C" void kernel_launch(void* const* d_in, const int* in_sizes, int n_in,
                              void* d_out, int out_size, void* d_ws, size_t ws_size,
                              hipStream_t stream)
{
  const float* x   = (const float*)d_in[0];
  const float* rw  = (const float*)d_in[1];
  const float* sup = (const float*)d_in[2];
  const float* sdn = (const float*)d_in[3];
  const float* rup = (const float*)d_in[4];
  const float* rdn = (const float*)d_in[5];
  float* out = (float*)d_out;

  char* w = (char*)d_ws;
  bf16*  xb       = (bf16*)(w + 0);           //  3,145,728 B
  bf16*  wupT     = (bf16*)(w + 3145728);     // 18,874,368 B  [4][3072][768]
  bf16*  wdn      = (bf16*)(w + 22020096);    // 18,874,368 B
  bf16*  hact     = (bf16*)(w + 40894464);    // 25,165,824 B
  bf16*  yc2      = (bf16*)(w + 66060288);    // 12,582,912 B  [2][4096][768]
  float* probs    = (float*)(w + 78643200);
  float* lse      = (float*)(w + 78675968);
  int*   tok_e    = (int*)(w + 78684160);
  int*   tok_slot = (int*)(w + 78700544);
  float* tok_w    = (float*)(w + 78716928);
  int*   list_tok = (int*)(w + 78733312);
  int*   cnt      = (int*)(w + 78766080);
  int*   base     = (int*)(w + 78766336);

  k_prep<<<2816, 256, 0, stream>>>(x, rw, sup, rup, xb, wupT,
                                   probs, lse, tok_e, tok_w);
  k_build_fin<<<1, 256, 0, stream>>>(tok_e, probs, lse, tok_slot, list_tok,
                                     cnt, base, out + (size_t)NTOK * DIMD);
  k_gemm_up<<<3840, 256, 0, stream>>>(xb, wupT, list_tok, cnt, base, hact,
                                      sdn, rdn, wdn);
  k_gemm_dn<<<768, 256, 0, stream>>>(hact, wdn, cnt, base, yc2);
  k_combine<<<2048, 192, 0, stream>>>(yc2, tok_e, tok_slot, tok_w, base, out);
}